// Round 6
// baseline (221.713 us; speedup 1.0000x reference)
//
#include <hip/hip_runtime.h>

// ---------------------------------------------------------------------------
// MozafariMNIST2018 SNN forward (training branch, max_layer==2) for MI355X.
//
//  4-kernel pipeline:
//   K1: conv1-MFMA || d_out zero-fill || w2 hi/lo bf16 prep || spk_in borders
//   K2: conv2 implicit-GEMM MFMA (256 thr, full-K unroll, double-buffered
//       weight regs to kill per-ks vmcnt(0) stalls)  [launched 2x this round
//       for timing attribution — idempotent]
//   K3: winmap (inlined) + exact-fp32 recompute of winner potentials
//   K4: get_k_winners (block 0) || sparse scatter (blocks 1-25)
//  All output values come from exact fp32 recompute -> absmax 0.
// ---------------------------------------------------------------------------

typedef unsigned short u16;
typedef __attribute__((ext_vector_type(8))) short short8;
typedef __attribute__((ext_vector_type(4))) float f32x4;
typedef __attribute__((ext_vector_type(4))) float float4v;

#define T_STEPS 15

// ws layout (byte offsets), all 16B aligned
#define WHI_OFF     0u         // 256*288 u16 = 147456 B
#define WLO_OFF     147456u    // 147456 B
#define SPKIN_OFF   294912u    // 15*30*82*82 u16 = 6051600 B
#define MAXV_OFF    6346512u   // 96000 f32
#define ARGM_OFF    6730512u   // 96000 i32
#define WINMAP_OFF  7114512u   // 6400 i32
#define POTWIN_OFF  7140112u   // 96000 f32 -> end 7524112

// K1 block ranges
#define N_CONV1  1500
#define N_FILL   2048
#define N_PREP   288
#define N_BORDER 18
#define K1_GRID  (N_CONV1 + N_FILL + N_PREP + N_BORDER)

static __device__ __forceinline__ u16 f2bf_rne(float f) {
  unsigned u = __float_as_uint(f);
  unsigned r = u + 0x7FFFu + ((u >> 16) & 1u);
  return (u16)(r >> 16);
}
static __device__ __forceinline__ float bf2f(u16 b) {
  return __uint_as_float(((unsigned)b) << 16);
}

// ---------------------------------------------------------------------------
// K1: conv1 (MFMA) || d_out fill || prep_wt || spk_in border ring
__global__ __launch_bounds__(256) void k1_kernel(
    const int* __restrict__ xin, const float* __restrict__ w1,
    const float* __restrict__ w2, u16* __restrict__ spk_in,
    u16* __restrict__ Whi, u16* __restrict__ Wlo,
    float4v* __restrict__ out4, int out_n4) {
  __shared__ u16 w1s[32 * 160];
  __shared__ u16 patch[6 * 20 * 20 + 320];   // + zero pad region
  __shared__ unsigned char fires[30 * 256];

  int tid = threadIdx.x;
  int b = blockIdx.x;

  if (b >= N_CONV1) {
    if (b < N_CONV1 + N_FILL) {
      int i = (b - N_CONV1) * 256 + tid;
      int stride = N_FILL * 256;
      float4v z = {0.f, 0.f, 0.f, 0.f};
      for (; i < out_n4; i += stride) out4[i] = z;
    } else if (b < N_CONV1 + N_FILL + N_PREP) {
      int g = (b - N_CONV1 - N_FILL) * 256 + tid;   // < 73728
      int f = g / 288, k = g % 288;
      u16 h = 0, l = 0;
      if (f < 250 && k < 270) {
        float w = w2[f * 270 + k];
        h = f2bf_rne(w);
        l = f2bf_rne(w - bf2f(h));
      }
      Whi[g] = h;
      Wlo[g] = l;
    } else {
      int idx = (b - N_CONV1 - N_FILL - N_PREP) * 256 + tid;
      for (int u = idx; u < 145800; u += N_BORDER * 256) {
        int tc = u / 324, i = u % 324;
        int row, col;
        if (i < 82) { row = 0; col = i; }
        else if (i < 164) { row = 81; col = i - 82; }
        else if (i < 244) { row = 1 + (i - 164); col = 0; }
        else { row = 1 + (i - 244); col = 81; }
        spk_in[(size_t)tc * 6724 + row * 82 + col] = 0;
      }
    }
    return;
  }

  // ---- conv1 + fire(15) + 2x2 OR pool -> spk_in interior ----
  int t = b / 100, tile = b % 100;
  int ty0 = (tile / 10) * 16, tx0 = (tile % 10) * 16;

  for (int idx = tid; idx < 32 * 160; idx += 256) {
    int f = idx / 160, k = idx % 160;
    w1s[idx] = (f < 30 && k < 150) ? f2bf_rne(w1[f * 150 + k]) : (u16)0;
  }
  for (int idx = tid; idx < 2720; idx += 256) {
    u16 v = 0;
    if (idx < 2400) {
      int c = idx / 400, rem = idx % 400;
      int r = rem / 20, col = rem % 20;
      int gy = ty0 + r - 2, gx = tx0 + col - 2;
      if ((unsigned)gy < 160u && (unsigned)gx < 160u)
        v = xin[((t * 6 + c) * 160 + gy) * 160 + gx] ? (u16)0x3F80 : (u16)0;
    }
    patch[idx] = v;
  }
  __syncthreads();

  int lane = tid & 63, wave = tid >> 6;
  int lrow = lane & 15, lgrp = lane >> 4;

  short8 afr[2][5];
#pragma unroll
  for (int m = 0; m < 2; ++m)
#pragma unroll
    for (int ks = 0; ks < 5; ++ks)
      afr[m][ks] =
          *(const short8*)&w1s[(m * 16 + lrow) * 160 + ks * 32 + lgrp * 8];

  int offs[5][8];
#pragma unroll
  for (int ks = 0; ks < 5; ++ks)
#pragma unroll
    for (int j = 0; j < 8; ++j) {
      int k = ks * 32 + lgrp * 8 + j;
      if (k < 150) {
        int c = k / 25, r = k % 25, ky = r / 5, kx = r % 5;
        offs[ks][j] = c * 400 + ky * 20 + kx;
      } else {
        offs[ks][j] = 2400;
      }
    }

  for (int ph = 0; ph < 4; ++ph) {
    int rrow = ph * 4 + wave;
    int pbase = rrow * 20 + lrow;
    short8 bfr[5];
#pragma unroll
    for (int ks = 0; ks < 5; ++ks)
#pragma unroll
      for (int j = 0; j < 8; ++j)
        bfr[ks][j] = (short)patch[offs[ks][j] + pbase];
    f32x4 acc0 = {0.f, 0.f, 0.f, 0.f}, acc1 = {0.f, 0.f, 0.f, 0.f};
#pragma unroll
    for (int ks = 0; ks < 5; ++ks) {
      acc0 = __builtin_amdgcn_mfma_f32_16x16x32_bf16(afr[0][ks], bfr[ks],
                                                     acc0, 0, 0, 0);
      acc1 = __builtin_amdgcn_mfma_f32_16x16x32_bf16(afr[1][ks], bfr[ks],
                                                     acc1, 0, 0, 0);
    }
#pragma unroll
    for (int r = 0; r < 4; ++r) {
      int f0 = lgrp * 4 + r;
      fires[f0 * 256 + rrow * 16 + lrow] = (acc0[r] >= 15.f);
      int f1 = 16 + lgrp * 4 + r;
      if (f1 < 30) fires[f1 * 256 + rrow * 16 + lrow] = (acc1[r] >= 15.f);
    }
  }
  __syncthreads();

  int pby0 = (ty0 >> 1) + 1, pbx0 = (tx0 >> 1) + 1;
  for (int idx = tid; idx < 30 * 64; idx += 256) {
    int f = idx >> 6, pp = idx & 63;
    int py = pp >> 3, px = pp & 7;
    const unsigned char* fb = &fires[f * 256 + py * 32 + px * 2];
    int v = fb[0] | fb[1] | fb[16] | fb[17];
    spk_in[((t * 30 + f) * 82 + pby0 + py) * 82 + pbx0 + px] =
        v ? (u16)0x3F80 : (u16)0;
  }
}

// ---------------------------------------------------------------------------
// K2: conv2 implicit-GEMM MFMA. grid 15*100, block 256 (4 waves).
// Block tile: 256 f (padded) x 64 pos (8x8), K = 288, hi+lo.
// Full K unroll + 2-deep register double-buffer of weight loads: the next
// ks's 8 global loads are issued BEFORE the current ks's 32 MFMAs, so the
// compiler emits counted waitcnts instead of a per-iteration vmcnt(0) drain.
__global__ __launch_bounds__(256) void conv2_kernel(
    const u16* __restrict__ spk_in, const u16* __restrict__ Whi,
    const u16* __restrict__ Wlo, float* __restrict__ maxv_ws,
    int* __restrict__ argm_ws) {
  __shared__ __align__(16) u16 lds[64 * 320 + 3008];  // Xt (swizzled) + patch
  u16* Xt = lds;
  u16* patch = lds + 20480;

  int tid = threadIdx.x;
  int b = blockIdx.x;
  int t = b / 100, tile = b % 100;
  int y0 = (tile / 10) * 8, x0 = (tile % 10) * 8;

  const u16* sb = spk_in + (size_t)t * 30 * 6724;
  for (int idx = tid; idx < 3000; idx += 256) {
    int c = idx / 100, rem = idx % 100;
    int dy = rem / 10, dx = rem % 10;
    patch[idx] = sb[c * 6724 + (y0 + dy) * 82 + (x0 + dx)];
  }
  __syncthreads();

  for (int task = tid; task < 2304; task += 256) {
    int p = task / 36, g = task % 36;
    int py = p >> 3, px = p & 7;
    short8 sv;
#pragma unroll
    for (int j = 0; j < 8; ++j) {
      int k = g * 8 + j;
      u16 v = 0;
      if (k < 270) {
        int c = k / 9, r9 = k % 9;
        int ky = r9 / 3, kx = r9 % 3;
        v = patch[(c * 10 + py + ky) * 10 + (px + kx)];
      }
      sv[j] = (short)v;
    }
    int off = (p * 320 + g * 8) ^ ((p & 7) << 3);
    *(short8*)(Xt + off) = sv;
  }
  __syncthreads();

  int lane = tid & 63, wave = tid >> 6;
  int lrow = lane & 15, lgrp = lane >> 4;
  int fbase = wave * 64;

  f32x4 acc[4][4];
#pragma unroll
  for (int i = 0; i < 4; ++i)
#pragma unroll
    for (int j = 0; j < 4; ++j) acc[i][j] = (f32x4){0.f, 0.f, 0.f, 0.f};

  const u16* whib = Whi + (fbase + lrow) * 288 + lgrp * 8;
  const u16* wlob = Wlo + (fbase + lrow) * 288 + lgrp * 8;
  int xorr = (lrow & 7) << 3;

  short8 ah[2][4], al[2][4];    // 2-deep weight double-buffer
#pragma unroll
  for (int ft = 0; ft < 4; ++ft) {
    ah[0][ft] = *(const short8*)(whib + ft * 16 * 288);
    al[0][ft] = *(const short8*)(wlob + ft * 16 * 288);
  }

#pragma unroll
  for (int ks = 0; ks < 9; ++ks) {
    int cur = ks & 1, nxt = cur ^ 1;
    if (ks < 8) {
#pragma unroll
      for (int ft = 0; ft < 4; ++ft) {
        ah[nxt][ft] =
            *(const short8*)(whib + ft * 16 * 288 + (ks + 1) * 32);
        al[nxt][ft] =
            *(const short8*)(wlob + ft * 16 * 288 + (ks + 1) * 32);
      }
    }
    short8 bfr[4];
#pragma unroll
    for (int pt = 0; pt < 4; ++pt) {
      int s = ((pt * 16 + lrow) * 320 + ks * 32 + lgrp * 8) ^ xorr;
      bfr[pt] = *(const short8*)(Xt + s);
    }
#pragma unroll
    for (int ft = 0; ft < 4; ++ft)
#pragma unroll
      for (int pt = 0; pt < 4; ++pt) {
        acc[ft][pt] = __builtin_amdgcn_mfma_f32_16x16x32_bf16(
            ah[cur][ft], bfr[pt], acc[ft][pt], 0, 0, 0);
        acc[ft][pt] = __builtin_amdgcn_mfma_f32_16x16x32_bf16(
            al[cur][ft], bfr[pt], acc[ft][pt], 0, 0, 0);
      }
  }

  // epilogue: threshold >=10, per-position max/argmax over f (first-max)
  __syncthreads();
  float* redv = (float*)lds;            // 256 f32
  int*   redi = (int*)(lds + 512);      // 256 i32

#pragma unroll
  for (int pt = 0; pt < 4; ++pt) {
    float bv = -1.f; int bf = 0;
#pragma unroll
    for (int ft = 0; ft < 4; ++ft)
#pragma unroll
      for (int r = 0; r < 4; ++r) {
        float v = acc[ft][pt][r];
        v = (v >= 10.f) ? v : 0.f;
        int f = fbase + ft * 16 + lgrp * 4 + r;
        if (v > bv) { bv = v; bf = f; }
      }
    {
      float ov = __shfl_xor(bv, 16); int of = __shfl_xor(bf, 16);
      if (ov > bv || (ov == bv && of < bf)) { bv = ov; bf = of; }
      ov = __shfl_xor(bv, 32); of = __shfl_xor(bf, 32);
      if (ov > bv || (ov == bv && of < bf)) { bv = ov; bf = of; }
    }
    if (lgrp == 0) {
      redv[wave * 64 + pt * 16 + lrow] = bv;
      redi[wave * 64 + pt * 16 + lrow] = bf;
    }
  }
  __syncthreads();
  if (tid < 64) {
    float bv = -1.f; int bf = 0x7fffffff;
#pragma unroll
    for (int w = 0; w < 4; ++w) {
      float v = redv[w * 64 + tid]; int f = redi[w * 64 + tid];
      if (v > bv || (v == bv && f < bf)) { bv = v; bf = f; }
    }
    int pos = (y0 + (tid >> 3)) * 80 + x0 + (tid & 7);
    maxv_ws[t * 6400 + pos] = bv;
    argm_ws[t * 6400 + pos] = bf;
  }
}

// ---------------------------------------------------------------------------
// K3: winmap (inlined per block) + exact fp32 recompute, LDS-staged patch.
__global__ __launch_bounds__(256) void recompute_kernel(
    const u16* __restrict__ spk_in, const float* __restrict__ w2,
    const float* __restrict__ maxv, const int* __restrict__ argm,
    int* __restrict__ winmap, float* __restrict__ potwin) {
  __shared__ u16 patch[30 * 18 * 18];

  int tid = threadIdx.x;
  int b = blockIdx.x;
  int t = b / 25, tile = b % 25;
  int ty0 = (tile / 5) * 16, tx0 = (tile % 5) * 16;

  const u16* base = spk_in + (size_t)t * 30 * 6724;
  for (int idx = tid; idx < 9720; idx += 256) {
    int c = idx / 324, rem = idx % 324;
    int dy = rem / 18, dx = rem % 18;
    patch[idx] = base[c * 6724 + (ty0 + dy) * 82 + (tx0 + dx)];
  }

  int py = tid >> 4, px = tid & 15;
  int pos = (ty0 + py) * 80 + tx0 + px;

  int nc = 0;
#pragma unroll
  for (int tt = 0; tt < T_STEPS; ++tt)
    nc += (maxv[tt * 6400 + pos] > 0.f) ? 1 : 0;
  int e = T_STEPS - nc; if (e > 14) e = 14;
  int win = argm[e * 6400 + pos];
  bool gate = maxv[14 * 6400 + pos] > 0.f;
  win = gate ? win : -1;
  if (t == 0) winmap[pos] = win;

  __syncthreads();

  float p = 0.f;
  if (win >= 0) {
    const float* wt = w2 + win * 270;
    float a = 0.f;
    for (int c = 0; c < 30; ++c) {        // exact fp32 chain (matches ref)
#pragma unroll
      for (int ky = 0; ky < 3; ++ky)
#pragma unroll
        for (int kx = 0; kx < 3; ++kx)
          a = fmaf(wt[c * 9 + ky * 3 + kx],
                   bf2f(patch[c * 324 + (py + ky) * 18 + (px + kx)]), a);
    }
    p = (a >= 10.f) ? a : 0.f;
  }
  potwin[t * 6400 + pos] = p;
}

// ---------------------------------------------------------------------------
// K4: block 0 = get_k_winners; blocks 1-25 = sparse scatter into zeroed d_out
__global__ __launch_bounds__(1024) void finalize_kernel(
    const int* __restrict__ winmap, const float* __restrict__ potwin,
    float* __restrict__ out, float* __restrict__ out_win) {
  __shared__ float tv[6400];
  __shared__ int   tf[6400];
  __shared__ float wv_s[16];
  __shared__ int   wk_s[16];
  __shared__ int   sh_w[4];
  __shared__ float vmax_s;

  int tid = threadIdx.x;
  int b = blockIdx.x;

  if (b > 0) {
    int pos = (b - 1) * 256 + (tid & 255);
    int tq = tid >> 8;
    int win = winmap[pos];
    if (win < 0) return;
    int tend = tq * 4 + 4; if (tend > T_STEPS) tend = T_STEPS;
    for (int t = tq * 4; t < tend; ++t) {
      float p = potwin[t * 6400 + pos];
      int o = (t * 250 + win) * 6400 + pos;
      out[o] = (p > 0.f) ? 1.f : 0.f;
      out[24000000 + o] = p;
    }
    return;
  }

  int lane = tid & 63, wid = tid >> 6;

  float localmax = 0.f;
  for (int pos = tid; pos < 6400; pos += 1024) {
    int win = winmap[pos];
    float val = 0.f; int nspk = 0;
    if (win >= 0) {
#pragma unroll
      for (int t = 0; t < T_STEPS; ++t)
        nspk += (potwin[t * 6400 + pos] > 0.f) ? 1 : 0;
      int first = T_STEPS - nspk; if (first > 14) first = 14;
      val = potwin[first * 6400 + pos];
      if (nspk > 0 && val > localmax) localmax = val;
    }
    tv[pos] = val;
    tf[pos] = ((win + 1) << 4) | nspk;
  }
#pragma unroll
  for (int m = 1; m < 64; m <<= 1)
    localmax = fmaxf(localmax, __shfl_xor(localmax, m));
  if (lane == 0) wv_s[wid] = localmax;
  __syncthreads();
  if (tid == 0) {
    float m = 0.f;
#pragma unroll
    for (int w = 0; w < 16; ++w) m = fmaxf(m, wv_s[w]);
    vmax_s = m * (float)T_STEPS;
  }
  __syncthreads();
  float v = vmax_s;

  for (int pos = tid; pos < 6400; pos += 1024) {
    int meta = tf[pos];
    int win = (meta >> 4) - 1, nspk = meta & 15;
    tf[pos] = win;
    tv[pos] = (win >= 0) ? (float)nspk * (tv[pos] + v) : 0.f;
  }
  __syncthreads();

  for (int it = 0; it < 8; ++it) {
    float bv = -1.f; int bk = 0x7fffffff;
    for (int pos = tid; pos < 6400; pos += 1024) {
      float tvv = tv[pos];
      int key = tf[pos] * 6400 + pos;
      if (tvv > bv || (tvv == bv && key < bk)) { bv = tvv; bk = key; }
    }
#pragma unroll
    for (int m = 1; m < 64; m <<= 1) {
      float ov = __shfl_xor(bv, m); int ok = __shfl_xor(bk, m);
      if (ov > bv || (ov == bv && ok < bk)) { bv = ov; bk = ok; }
    }
    if (lane == 0) { wv_s[wid] = bv; wk_s[wid] = bk; }
    __syncthreads();
    if (tid == 0) {
      float mbv = -1.f; int mbk = 0x7fffffff;
#pragma unroll
      for (int w = 0; w < 16; ++w) {
        float ov = wv_s[w]; int ok = wk_s[w];
        if (ov > mbv || (ov == mbv && ok < mbk)) { mbv = ov; mbk = ok; }
      }
      int f = -1, r = -1, c = -1, valid = 0;
      if (mbv != 0.f) {
        f = mbk / 6400; int pos = mbk % 6400;
        r = pos / 80; c = pos % 80;
        valid = 1;
      }
      out_win[it * 3 + 0] = (float)f;
      out_win[it * 3 + 1] = (float)r;
      out_win[it * 3 + 2] = (float)c;
      sh_w[0] = f; sh_w[1] = r; sh_w[2] = c; sh_w[3] = valid;
    }
    __syncthreads();
    if (sh_w[3]) {
      int wf = sh_w[0], wr = sh_w[1], wc = sh_w[2];
      for (int pos = tid; pos < 6400; pos += 1024) {
        int r = pos / 80, c = pos % 80;
        int dr = r - wr; if (dr < 0) dr = -dr;
        int dc = c - wc; if (dc < 0) dc = -dc;
        if (tf[pos] == wf || (dr <= 1 && dc <= 1)) tv[pos] = 0.f;
      }
    }
    __syncthreads();
  }
}

// ---------------------------------------------------------------------------
extern "C" void kernel_launch(void* const* d_in, const int* in_sizes, int n_in,
                              void* d_out, int out_size, void* d_ws,
                              size_t ws_size, hipStream_t stream) {
  const int*   xin = (const int*)d_in[0];
  const float* w1  = (const float*)d_in[1];
  const float* w2  = (const float*)d_in[2];
  float* out = (float*)d_out;
  char*  ws  = (char*)d_ws;

  u16*   Whi    = (u16*)(ws + WHI_OFF);
  u16*   Wlo    = (u16*)(ws + WLO_OFF);
  u16*   spk_in = (u16*)(ws + SPKIN_OFF);
  float* maxv   = (float*)(ws + MAXV_OFF);
  int*   argm   = (int*)(ws + ARGM_OFF);
  int*   winmap = (int*)(ws + WINMAP_OFF);
  float* potwin = (float*)(ws + POTWIN_OFF);

  k1_kernel<<<K1_GRID, 256, 0, stream>>>(xin, w1, w2, spk_in, Whi, Wlo,
                                         (float4v*)d_out, out_size / 4);
  // conv2 launched TWICE this round (idempotent) for timing attribution:
  // dur_us = rest + 2*conv2.
  conv2_kernel<<<1500, 256, 0, stream>>>(spk_in, Whi, Wlo, maxv, argm);
  conv2_kernel<<<1500, 256, 0, stream>>>(spk_in, Whi, Wlo, maxv, argm);
  recompute_kernel<<<375, 256, 0, stream>>>(spk_in, w2, maxv, argm, winmap,
                                            potwin);
  finalize_kernel<<<26, 1024, 0, stream>>>(winmap, potwin, out,
                                           out + 48000000);
}